// Round 5
// baseline (239.335 us; speedup 1.0000x reference)
//
#include <hip/hip_runtime.h>
#include <hip/hip_bf16.h>

typedef __attribute__((ext_vector_type(8))) short short8;
typedef __attribute__((ext_vector_type(4))) float f32x4;
typedef __attribute__((ext_vector_type(16))) float f32x16;
typedef unsigned short u16t;
typedef unsigned int u32t;

#define MFMA16(a, b, c) __builtin_amdgcn_mfma_f32_16x16x32_bf16((a), (b), (c), 0, 0, 0)
#define MFMA32(a, b, c) __builtin_amdgcn_mfma_f32_32x32x16_bf16((a), (b), (c), 0, 0, 0)

__device__ __forceinline__ u16t f2b(float f) {
    union { float f; u32t u; } v; v.f = f;
    u32t u = v.u + 0x7FFFu + ((v.u >> 16) & 1u);
    return (u16t)(u >> 16);
}
__device__ __forceinline__ u32t encf(float f) {
    union { float f; u32t u; } v; v.f = f;
    return (v.u & 0x80000000u) ? ~v.u : (v.u | 0x80000000u);
}
__device__ __forceinline__ float decf(u32t u) {
    union { u32t u; float f; } v;
    v.u = (u & 0x80000000u) ? (u ^ 0x80000000u) : ~u;
    return v.f;
}
__device__ __forceinline__ float fexp2(float x) {
#if __has_builtin(__builtin_amdgcn_exp2f)
    return __builtin_amdgcn_exp2f(x);
#else
    return __expf(x * 0.6931471805599453f);
#endif
}
__device__ __forceinline__ void gload16(const u16t* g, u16t* l) {
    __builtin_amdgcn_global_load_lds((const __attribute__((address_space(1))) void*)g,
                                     (__attribute__((address_space(3))) void*)l, 16, 0, 0);
}

// ---------------- cast fp32 -> bf16, 4 elems/thread ----------------
__global__ __launch_bounds__(256) void k_cast_x(const float* __restrict__ x, u16t* __restrict__ xb) {
    int i = blockIdx.x * 256 + threadIdx.x;
    float4 v = ((const float4*)x)[i];
    ushort4 o;
    o.x = f2b(v.x); o.y = f2b(v.y); o.z = f2b(v.z); o.w = f2b(v.w);
    ((ushort4*)xb)[i] = o;
}

// ---------------- transpose + cast weights: WT[n][k] = W[k][n] ----------------
__global__ __launch_bounds__(256) void k_transpose(const float* __restrict__ W, u16t* __restrict__ WT,
                                                   int K, int N, int NP) {
    __shared__ float t[32][33];
    int n0 = blockIdx.x * 32, k0 = blockIdx.y * 32;
    int tx = threadIdx.x, ty = threadIdx.y;  // 32 x 8
    for (int i = 0; i < 32; i += 8) {
        int k = k0 + ty + i, n = n0 + tx;
        t[ty + i][tx] = (n < N) ? W[(size_t)k * N + n] : 0.f;
    }
    __syncthreads();
    for (int i = 0; i < 32; i += 8) {
        int n = n0 + ty + i, k = k0 + tx;
        if (n < NP) WT[(size_t)n * K + k] = f2b(t[tx][ty + i]);
    }
}

// ---------------- fused bias: bias_f[n] = b_proj . w_head[:,n] + b_head[n] ----------------
__global__ __launch_bounds__(256) void k_bias_f(const float* __restrict__ bproj, const float* __restrict__ whead,
                                                const float* __restrict__ bhead, float* __restrict__ bf) {
    __shared__ float red[256];
    int t = threadIdx.x;
    int c = t & 15;
    int jg = t >> 4;
    int n = blockIdx.x * 16 + c;
    float s = 0.f;
    if (n < 1000) {
#pragma unroll 4
        for (int j = jg * 48; j < jg * 48 + 48; ++j)
            s += bproj[j] * whead[j * 1000 + n];
    }
    red[t] = s;
    __syncthreads();
    for (int off = 128; off >= 16; off >>= 1) {
        if (t < off) red[t] += red[t + off];
        __syncthreads();
    }
    if (t < 16) {
        int nn = blockIdx.x * 16 + t;
        bf[nn] = (nn < 1000) ? (red[t] + bhead[nn]) : 0.f;
    }
}

// ---------------- out init / decode ----------------
__global__ __launch_bounds__(256) void k_init_out(u32t* __restrict__ o, int n) {
    int i = blockIdx.x * 256 + threadIdx.x;
    if (i < n) o[i] = 0u;
}
__global__ __launch_bounds__(256) void k_decode_out(u32t* __restrict__ o, int n) {
    int i = blockIdx.x * 256 + threadIdx.x;
    if (i < n) {
        float f = decf(o[i]);
        ((float*)o)[i] = f;
    }
}

// ---------------- GEMM v6: C[M,N] = A[M,K] * BT[N,K]^T, bf16 in, fp32 acc ----------------
// BM=256 x BN=128 x BK=64, 512 thr / 8 waves (4M x 2N), wave tile 64x64, acc[4][4].
// R4 post-mortem: 2-phase schedules are structurally capped (~300 TF here); swizzle/AI/
// occupancy grafts all null (matches m252 regime gate). k_flash in this same file hits
// >=750 TF with: 3 LDS buffers + 2-tile-deep prefetch + counted vmcnt (never drains).
// v6 = that structure + per-phase MFMA clusters:
//  - 3 buffers (144KB LDS): tile t reads buf t%3 while t+1 landed and t+2 in flight.
//    vmcnt(6) at tile top: t's 6 loads are oldest in FIFO -> guaranteed landed; t+1's 6
//    (+t+2 partials) stay in flight. vmcnt(0) only on the last tile.
//  - per K-tile 4 phases {stage-issue || ds_read subtile -> barrier -> setprio(1)
//    8xMFMA setprio(0) -> barrier}; stage loads spread 2,2,1,1 across phases.
//  - LDS chunk-XOR swizzle kept byte-identical from R4 (measured 0 bank conflicts).
#define BM 256
#define BN 128

#define QSCALE 0.18033688011112042f

// EPI 0: qkv scatter; EPI 2: +bias col-max atomic; EPI 3: plain bf16 store
template <int EPI>
__global__ __launch_bounds__(512, 1) void k_gemm9(const u16t* __restrict__ A, const u16t* __restrict__ BT,
                                                  int M, int N, int K,
                                                  u16t* __restrict__ Cb, const float* __restrict__ bias,
                                                  u32t* __restrict__ omax) {
    __shared__ alignas(16) u16t Asf[3][2][8192];   // [buf][kk][256*32 swizzled]  96KB
    __shared__ alignas(16) u16t Bsf[3][2][4096];   // [buf][kk][128*32 swizzled]  48KB

    int tid = threadIdx.x;
    int lane = tid & 63, wid = tid >> 6;
    int wr = wid >> 1, wc = wid & 1;           // 4 x 2 wave grid
    int g = lane >> 4, l15 = lane & 15;

    // XCD-aware chunked swizzle (bijective: gridDim.x % 8 == 0 for all launches here)
    int nwg = gridDim.x;
    int bid = blockIdx.x;
    int wg = (bid & 7) * (nwg >> 3) + (bid >> 3);
    int nx = N >> 7;
    int bx = wg % nx, by = wg / nx;
    int m0 = by * BM, n0 = bx * BN;

    f32x4 acc[4][4];
    for (int i = 0; i < 4; i++)
        for (int j = 0; j < 4; j++) acc[i][j] = (f32x4){0.f, 0.f, 0.f, 0.f};

    // ---- staging maps (R4-verified, zero-conflict swizzle) ----
    // A: 4 chunks/thread (2 per kk-slab). cl lane-linear in slab; cd = cl ^ ((cl>>3)&3).
    const u16t* srcA[4]; int offA[4];
#pragma unroll
    for (int ii = 0; ii < 4; ii++) {
        int kk = ii >> 1;
        int cl = wid * 128 + (ii & 1) * 64 + lane;      // 0..1023
        int cd = cl ^ ((cl >> 3) & 3);
        srcA[ii] = A + (size_t)(m0 + (cd >> 2)) * K + kk * 32 + (cd & 3) * 8;
        offA[ii] = kk * 8192 + cl * 8;
    }
    // B: 2 chunks/thread over 2 kk-slabs of [128][4 x 16B]
    const u16t* srcB[2]; int offB[2];
#pragma unroll
    for (int jj = 0; jj < 2; jj++) {
        int c = (wid * 2 + jj) * 64 + lane;             // 0..1023
        int kk = c >> 9, cl = c & 511;
        int cd = cl ^ ((cl >> 3) & 3);
        srcB[jj] = BT + (size_t)(n0 + (cd >> 2)) * K + kk * 32 + (cd & 3) * 8;
        offB[jj] = kk * 4096 + cl * 8;
    }

    // ---- swizzled ds_read element offsets within a kk-slab ----
    int aoff[4], boff[4];
#pragma unroll
    for (int i = 0; i < 4; i++) {
        int lin = ((wr * 64 + i * 16 + l15) << 6) + (g << 4);     // bytes
        aoff[i] = (lin ^ (((lin >> 7) & 3) << 4)) >> 1;           // elems
    }
#pragma unroll
    for (int j = 0; j < 4; j++) {
        int lin = ((wc * 64 + j * 16 + l15) << 6) + (g << 4);
        boff[j] = (lin ^ (((lin >> 7) & 3) << 4)) >> 1;
    }

    const int NT = K >> 6;  // 12 K-tiles of 64

    // prologue: stage tile 0 -> buf 0, tile 1 -> buf 1 (12 loads, FIFO order t0 then t1)
#pragma unroll
    for (int ii = 0; ii < 4; ii++) gload16(srcA[ii], &Asf[0][0][0] + offA[ii]);
#pragma unroll
    for (int jj = 0; jj < 2; jj++) gload16(srcB[jj], &Bsf[0][0][0] + offB[jj]);
#pragma unroll
    for (int ii = 0; ii < 4; ii++) gload16(srcA[ii] + 64, &Asf[1][0][0] + offA[ii]);
#pragma unroll
    for (int jj = 0; jj < 2; jj++) gload16(srcB[jj] + 64, &Bsf[1][0][0] + offB[jj]);

#pragma unroll 1
    for (int t = 0; t < NT; ++t) {
        const int cb = t % 3;
        const int sb = (t + 2) % 3;
        const bool st = (t + 2) < NT;
        const int ko = (t + 2) << 6;

        // tile t's 6 loads are the oldest outstanding; keep t+1 (and t+2 partials) in flight
        if (t + 1 < NT) {
            asm volatile("s_waitcnt vmcnt(6)" ::: "memory");
        } else {
            asm volatile("s_waitcnt vmcnt(0)" ::: "memory");
        }
        __builtin_amdgcn_s_barrier();

        const u16t* Ab = &Asf[cb][0][0];
        const u16t* Bb = &Bsf[cb][0][0];
        u16t* Asb = &Asf[sb][0][0];
        u16t* Bsb = &Bsf[sb][0][0];

        short8 a0, a1, a2, a3, b0, b1, b2, b3;

        // ---- phase 0: kk0, i={0,1} ----
        if (st) { gload16(srcA[0] + ko, Asb + offA[0]); gload16(srcA[1] + ko, Asb + offA[1]); }
        a0 = *(const short8*)&Ab[aoff[0]];
        a1 = *(const short8*)&Ab[aoff[1]];
        b0 = *(const short8*)&Bb[boff[0]];
        b1 = *(const short8*)&Bb[boff[1]];
        b2 = *(const short8*)&Bb[boff[2]];
        b3 = *(const short8*)&Bb[boff[3]];
        __builtin_amdgcn_s_barrier();
        __builtin_amdgcn_s_setprio(1);
        acc[0][0] = MFMA16(a0, b0, acc[0][0]); acc[0][1] = MFMA16(a0, b1, acc[0][1]);
        acc[0][2] = MFMA16(a0, b2, acc[0][2]); acc[0][3] = MFMA16(a0, b3, acc[0][3]);
        acc[1][0] = MFMA16(a1, b0, acc[1][0]); acc[1][1] = MFMA16(a1, b1, acc[1][1]);
        acc[1][2] = MFMA16(a1, b2, acc[1][2]); acc[1][3] = MFMA16(a1, b3, acc[1][3]);
        __builtin_amdgcn_s_setprio(0);
        __builtin_amdgcn_s_barrier();

        // ---- phase 1: kk0, i={2,3} (reuse b0..b3) ----
        if (st) { gload16(srcA[2] + ko, Asb + offA[2]); gload16(srcA[3] + ko, Asb + offA[3]); }
        a2 = *(const short8*)&Ab[aoff[2]];
        a3 = *(const short8*)&Ab[aoff[3]];
        __builtin_amdgcn_s_barrier();
        __builtin_amdgcn_s_setprio(1);
        acc[2][0] = MFMA16(a2, b0, acc[2][0]); acc[2][1] = MFMA16(a2, b1, acc[2][1]);
        acc[2][2] = MFMA16(a2, b2, acc[2][2]); acc[2][3] = MFMA16(a2, b3, acc[2][3]);
        acc[3][0] = MFMA16(a3, b0, acc[3][0]); acc[3][1] = MFMA16(a3, b1, acc[3][1]);
        acc[3][2] = MFMA16(a3, b2, acc[3][2]); acc[3][3] = MFMA16(a3, b3, acc[3][3]);
        __builtin_amdgcn_s_setprio(0);
        __builtin_amdgcn_s_barrier();

        // ---- phase 2: kk1, i={0,1} ----
        if (st) { gload16(srcB[0] + ko, Bsb + offB[0]); }
        a0 = *(const short8*)&Ab[8192 + aoff[0]];
        a1 = *(const short8*)&Ab[8192 + aoff[1]];
        b0 = *(const short8*)&Bb[4096 + boff[0]];
        b1 = *(const short8*)&Bb[4096 + boff[1]];
        b2 = *(const short8*)&Bb[4096 + boff[2]];
        b3 = *(const short8*)&Bb[4096 + boff[3]];
        __builtin_amdgcn_s_barrier();
        __builtin_amdgcn_s_setprio(1);
        acc[0][0] = MFMA16(a0, b0, acc[0][0]); acc[0][1] = MFMA16(a0, b1, acc[0][1]);
        acc[0][2] = MFMA16(a0, b2, acc[0][2]); acc[0][3] = MFMA16(a0, b3, acc[0][3]);
        acc[1][0] = MFMA16(a1, b0, acc[1][0]); acc[1][1] = MFMA16(a1, b1, acc[1][1]);
        acc[1][2] = MFMA16(a1, b2, acc[1][2]); acc[1][3] = MFMA16(a1, b3, acc[1][3]);
        __builtin_amdgcn_s_setprio(0);
        __builtin_amdgcn_s_barrier();

        // ---- phase 3: kk1, i={2,3} ----
        if (st) { gload16(srcB[1] + ko, Bsb + offB[1]); }
        a2 = *(const short8*)&Ab[8192 + aoff[2]];
        a3 = *(const short8*)&Ab[8192 + aoff[3]];
        __builtin_amdgcn_s_barrier();
        __builtin_amdgcn_s_setprio(1);
        acc[2][0] = MFMA16(a2, b0, acc[2][0]); acc[2][1] = MFMA16(a2, b1, acc[2][1]);
        acc[2][2] = MFMA16(a2, b2, acc[2][2]); acc[2][3] = MFMA16(a2, b3, acc[2][3]);
        acc[3][0] = MFMA16(a3, b0, acc[3][0]); acc[3][1] = MFMA16(a3, b1, acc[3][1]);
        acc[3][2] = MFMA16(a3, b2, acc[3][2]); acc[3][3] = MFMA16(a3, b3, acc[3][3]);
        __builtin_amdgcn_s_setprio(0);
        __builtin_amdgcn_s_barrier();   // tile boundary: all waves done reading buf cb
    }

    if constexpr (EPI == 0) {
        // scatter: Q,K -> [B,H,N,64]; V -> V^T [B,H,64,2048] with kv bits2,3 swapped
        for (int i = 0; i < 4; i++)
            for (int j = 0; j < 4; j++)
                for (int r = 0; r < 4; r++) {
                    int row = m0 + wr * 64 + i * 16 + g * 4 + r;
                    int col = n0 + wc * 64 + j * 16 + l15;
                    int t = col / 768, rem = col - t * 768;
                    int hh = rem >> 6, d = rem & 63;
                    int bb = row >> 11, n = row & 2047;
                    float v = acc[i][j][r];
                    size_t idx;
                    if (t == 0) {
                        v *= QSCALE;
                        idx = ((size_t)(bb * 12 + hh)) * 131072 + (size_t)n * 64 + d;
                    } else if (t == 1) {
                        idx = ((size_t)(48 + bb * 12 + hh)) * 131072 + (size_t)n * 64 + d;
                    } else {
                        int np = (n & ~12) | ((n & 4) << 1) | ((n & 8) >> 1);
                        idx = ((size_t)(96 + bb * 12 + hh)) * 131072 + (size_t)d * 2048 + np;
                    }
                    Cb[idx] = f2b(v);
                }
    } else if constexpr (EPI == 3) {
        for (int i = 0; i < 4; i++)
            for (int j = 0; j < 4; j++)
                for (int r = 0; r < 4; r++) {
                    int row = m0 + wr * 64 + i * 16 + g * 4 + r;
                    int col = n0 + wc * 64 + j * 16 + l15;
                    Cb[(size_t)row * N + col] = f2b(acc[i][j][r]);
                }
    } else {
        __shared__ float smax[4][BN];
        float cmax[4];
        for (int j = 0; j < 4; j++) {
            float m = -3.0e38f;
            for (int i = 0; i < 4; i++)
                for (int r = 0; r < 4; r++) m = fmaxf(m, acc[i][j][r]);
            m = fmaxf(m, __shfl_xor(m, 16));
            m = fmaxf(m, __shfl_xor(m, 32));
            cmax[j] = m;
        }
        __syncthreads();
        if (lane < 16)
            for (int j = 0; j < 4; j++) smax[wr][wc * 64 + j * 16 + lane] = cmax[j];
        __syncthreads();
        if (tid < BN) {
            int col = n0 + tid;
            if (col < 1000) {
                float m = fmaxf(fmaxf(smax[0][tid], smax[1][tid]),
                                fmaxf(smax[2][tid], smax[3][tid])) + bias[col];
                int b = m0 >> 11;   // BM=256 divides 2048
                atomicMax(&omax[b * 1000 + col], encf(m));
            }
        }
    }
}

// ---------------- flash attention v7: fixed-max softmax with raw v_exp_f32, MFMA l-sum ----------------
__global__ __launch_bounds__(256) void k_flash(const u16t* __restrict__ QKV, u16t* __restrict__ AO) {
    __shared__ alignas(16) u16t Kc[3][4096];
    __shared__ alignas(16) u16t Vc[3][4096];

    const int tid = threadIdx.x;
    const int lane = tid & 63;
    const int h = lane >> 5;
    const int l31 = lane & 31;
    const int w = tid >> 6;
    const int wk = ((blockIdx.x & 7) * 96) + (blockIdx.x >> 3);
    const int qt = wk & 15;
    const int hb = wk >> 4;           // b*12 + head
    const int head = hb % 12, b = hb / 12;
    const u16t* Qg = QKV + ((size_t)hb) * 131072;
    const u16t* Kg = QKV + ((size_t)(48 + hb)) * 131072;
    const u16t* Vg = QKV + ((size_t)(96 + hb)) * 131072;  // V^T [64][2048], kv bits2,3 pre-swapped
    const int q0w = qt * 128 + w * 32;

    short8 qf[4];
#pragma unroll
    for (int ks = 0; ks < 4; ++ks)
        qf[ks] = *(const short8*)&Qg[(size_t)(q0w + l31) * 64 + ks * 16 + h * 8];
    asm volatile("s_waitcnt vmcnt(0)" ::: "memory");

    short8 vone;
#pragma unroll
    for (int e = 0; e < 8; ++e) vone[e] = (short)0x3F80;

    f32x16 o0, o1, lsum;
#pragma unroll
    for (int r = 0; r < 16; ++r) { o0[r] = 0.f; o1[r] = 0.f; lsum[r] = 0.f; }

    auto stage = [&](int bi, int kv0) {
#pragma unroll
        for (int c = 0; c < 2; ++c) {
            int ic = c * 256 + tid;
            int ss = ic >> 8, ks = (ic >> 6) & 3, l6 = ic & 63;
            int hh = l6 >> 5, lq = l6 & 31;
            const u16t* gs = Kg + ((size_t)(kv0 + ss * 32 + lq) << 6) + ks * 16 + hh * 8;
            gload16(gs, &Kc[bi][ic * 8]);
        }
#pragma unroll
        for (int c = 0; c < 2; ++c) {
            int ic = c * 256 + tid;
            int jb = ic >> 8, ks = (ic >> 6) & 3, l6 = ic & 63;
            int hh = l6 >> 5, ld = l6 & 31;
            const u16t* gs = Vg + (size_t)(jb * 32 + ld) * 2048 + kv0 + ks * 16 + hh * 8;
            gload16(gs, &Vc[bi][ic * 8]);
        }
    };

    stage(0, 0);
    stage(1, 64);

#pragma unroll 1
    for (int t = 0; t < 32; ++t) {
        const int cur = t % 3;
        if (t < 30) {
            stage((t + 2) % 3, (t + 2) * 64);
            asm volatile("s_waitcnt vmcnt(8)" ::: "memory");
        } else if (t == 30) {
            asm volatile("s_waitcnt vmcnt(4)" ::: "memory");
        } else {
            asm volatile("s_waitcnt vmcnt(0)" ::: "memory");
        }
        __builtin_amdgcn_s_barrier();

        const u16t* Kb = &Kc[cur][0];
        const u16t* Vb = &Vc[cur][0];

        f32x16 s0, s1;
#pragma unroll
        for (int r = 0; r < 16; ++r) { s0[r] = 0.f; s1[r] = 0.f; }
        __builtin_amdgcn_s_setprio(1);
#pragma unroll
        for (int ks = 0; ks < 4; ++ks) {
            short8 k0 = *(const short8*)&Kb[(ks * 64 + lane) * 8];
            short8 k1 = *(const short8*)&Kb[((4 + ks) * 64 + lane) * 8];
            s0 = MFMA32(k0, qf[ks], s0);
            s1 = MFMA32(k1, qf[ks], s1);
        }
        __builtin_amdgcn_s_setprio(0);

        // P = exp2(S), packed straight into A-fragments (fixed max = 0)
        short8 pf[4];
        auto packhalf = [&](const f32x16& sv, int half, int idx) {
            union { u32t wu[4]; short8 v; } u;
#pragma unroll
            for (int wq = 0; wq < 4; ++wq) {
                float lo = fexp2(sv[half * 8 + 2 * wq]);
                float hi = fexp2(sv[half * 8 + 2 * wq + 1]);
                asm("v_cvt_pk_bf16_f32 %0, %1, %2" : "=v"(u.wu[wq]) : "v"(lo), "v"(hi));
            }
            pf[idx] = u.v;
        };
        packhalf(s0, 0, 0);
        packhalf(s0, 1, 1);
        packhalf(s1, 0, 2);
        packhalf(s1, 1, 3);

        // PV: O += P * V ; l-sum via ones-operand MFMA
        __builtin_amdgcn_s_setprio(1);
#pragma unroll
        for (int ks = 0; ks < 4; ++ks) {
            short8 v0 = *(const short8*)&Vb[(ks * 64 + lane) * 8];
            short8 v1 = *(const short8*)&Vb[((4 + ks) * 64 + lane) * 8];
            o0 = MFMA32(pf[ks], v0, o0);
            o1 = MFMA32(pf[ks], v1, o1);
            lsum = MFMA32(pf[ks], vone, lsum);
        }
        __builtin_amdgcn_s_setprio(0);

        asm volatile("s_waitcnt lgkmcnt(0)" ::: "memory");
        __builtin_amdgcn_s_barrier();
    }

    // normalize + store
#pragma unroll
    for (int r = 0; r < 16; ++r) {
        int q = (r & 3) + 8 * (r >> 2) + 4 * h;
        float rn = 1.0f / lsum[r];
        u16t* dst = AO + (size_t)(b * 2048 + q0w + q) * 768 + head * 64;
        dst[l31] = f2b(o0[r] * rn);
        dst[32 + l31] = f2b(o1[r] * rn);
    }
}

extern "C" void kernel_launch(void* const* d_in, const int* in_sizes, int n_in,
                              void* d_out, int out_size, void* d_ws, size_t ws_size,
                              hipStream_t stream) {
    const float* x = (const float*)d_in[0];
    const float* w_qkv = (const float*)d_in[1];
    const float* w_proj = (const float*)d_in[2];
    const float* b_proj = (const float*)d_in[3];
    const float* w_head = (const float*)d_in[4];
    const float* b_head = (const float*)d_in[5];

    char* ws = (char*)d_ws;
    u16t* xb = (u16t*)(ws);                        // 8192x768 bf16      12,582,912 B
    u16t* wqkvT = (u16t*)(ws + 12582912);          // 2304x768           3,538,944
    u16t* wheadT = (u16t*)(ws + 16121856);         // 1024x768 (padded)  1,572,864
    u16t* wprojb = (u16t*)(ws + 17694720);         // 768x768 row-major  1,179,648
    u16t* qkv = (u16t*)(ws + 18874368);            // [3,4,12,...]       37,748,736
    u16t* ao = (u16t*)(ws + 56623104);             // 8192x768           12,582,912
    u16t* WfT = (u16t*)(ws + 69206016);            // 1024x768           1,572,864
    float* bias_f = (float*)(ws + 70778880);       // 1024 f32           4,096

    dim3 tb(32, 8);
    k_cast_x<<<6144, 256, 0, stream>>>(x, xb);
    k_cast_x<<<576, 256, 0, stream>>>(w_proj, (u16t*)wprojb);
    k_transpose<<<dim3(2304 / 32, 768 / 32), tb, 0, stream>>>(w_qkv, wqkvT, 768, 2304, 2304);
    k_transpose<<<dim3(1024 / 32, 768 / 32), tb, 0, stream>>>(w_head, wheadT, 768, 1000, 1024);
    k_init_out<<<16, 256, 0, stream>>>((u32t*)d_out, 4000);
    k_bias_f<<<64, 256, 0, stream>>>(b_proj, w_head, b_head, bias_f);

    // WfT[n][k] = sum_j whead[j][n] * wproj[k][j]  (fused proj@head weight, transposed)
    // grid 4x6 = 24 blocks (%8==0)
    k_gemm9<3><<<24, 512, 0, stream>>>(wheadT, wprojb, 1024, 768, 768, WfT, nullptr, nullptr);

    // qkv = x @ w_qkv  (scatter: Q scaled, K row-major, V transposed + kv-perm)
    // grid 18x32 = 576 blocks (%8==0)
    k_gemm9<0><<<576, 512, 0, stream>>>(xb, wqkvT, 8192, 2304, 768, qkv, nullptr, nullptr);
    // attention
    k_flash<<<768, 256, 0, stream>>>(qkv, ao);
    // fused (proj+head) + bias + max-over-N (atomic, encoded)
    // grid 8x32 = 256 blocks (%8==0)
    k_gemm9<2><<<256, 512, 0, stream>>>(ao, WfT, 8192, 1024, 768, nullptr, bias_f, (u32t*)d_out);

    k_decode_out<<<16, 256, 0, stream>>>((u32t*)d_out, 4000);
}

// Round 6
// 207.812 us; speedup vs baseline: 1.1517x; 1.1517x over previous
//
#include <hip/hip_runtime.h>
#include <hip/hip_bf16.h>

typedef __attribute__((ext_vector_type(8))) short short8;
typedef __attribute__((ext_vector_type(4))) float f32x4;
typedef __attribute__((ext_vector_type(16))) float f32x16;
typedef unsigned short u16t;
typedef unsigned int u32t;

#define MFMA16(a, b, c) __builtin_amdgcn_mfma_f32_16x16x32_bf16((a), (b), (c), 0, 0, 0)
#define MFMA32(a, b, c) __builtin_amdgcn_mfma_f32_32x32x16_bf16((a), (b), (c), 0, 0, 0)

__device__ __forceinline__ u16t f2b(float f) {
    union { float f; u32t u; } v; v.f = f;
    u32t u = v.u + 0x7FFFu + ((v.u >> 16) & 1u);
    return (u16t)(u >> 16);
}
__device__ __forceinline__ u32t encf(float f) {
    union { float f; u32t u; } v; v.f = f;
    return (v.u & 0x80000000u) ? ~v.u : (v.u | 0x80000000u);
}
__device__ __forceinline__ float decf(u32t u) {
    union { u32t u; float f; } v;
    v.u = (u & 0x80000000u) ? (u ^ 0x80000000u) : ~u;
    return v.f;
}
__device__ __forceinline__ float fexp2(float x) {
#if __has_builtin(__builtin_amdgcn_exp2f)
    return __builtin_amdgcn_exp2f(x);
#else
    return __expf(x * 0.6931471805599453f);
#endif
}
__device__ __forceinline__ void gload16(const u16t* g, u16t* l) {
    __builtin_amdgcn_global_load_lds((const __attribute__((address_space(1))) void*)g,
                                     (__attribute__((address_space(3))) void*)l, 16, 0, 0);
}

// ---------------- cast fp32 -> bf16, 4 elems/thread ----------------
__global__ __launch_bounds__(256) void k_cast_x(const float* __restrict__ x, u16t* __restrict__ xb) {
    int i = blockIdx.x * 256 + threadIdx.x;
    float4 v = ((const float4*)x)[i];
    ushort4 o;
    o.x = f2b(v.x); o.y = f2b(v.y); o.z = f2b(v.z); o.w = f2b(v.w);
    ((ushort4*)xb)[i] = o;
}

// ---------------- transpose + cast weights: WT[n][k] = W[k][n] ----------------
__global__ __launch_bounds__(256) void k_transpose(const float* __restrict__ W, u16t* __restrict__ WT,
                                                   int K, int N, int NP) {
    __shared__ float t[32][33];
    int n0 = blockIdx.x * 32, k0 = blockIdx.y * 32;
    int tx = threadIdx.x, ty = threadIdx.y;  // 32 x 8
    for (int i = 0; i < 32; i += 8) {
        int k = k0 + ty + i, n = n0 + tx;
        t[ty + i][tx] = (n < N) ? W[(size_t)k * N + n] : 0.f;
    }
    __syncthreads();
    for (int i = 0; i < 32; i += 8) {
        int n = n0 + ty + i, k = k0 + tx;
        if (n < NP) WT[(size_t)n * K + k] = f2b(t[tx][ty + i]);
    }
}

// ---------------- fused bias: bias_f[n] = b_proj . w_head[:,n] + b_head[n] ----------------
__global__ __launch_bounds__(256) void k_bias_f(const float* __restrict__ bproj, const float* __restrict__ whead,
                                                const float* __restrict__ bhead, float* __restrict__ bf) {
    __shared__ float red[256];
    int t = threadIdx.x;
    int c = t & 15;
    int jg = t >> 4;
    int n = blockIdx.x * 16 + c;
    float s = 0.f;
    if (n < 1000) {
#pragma unroll 4
        for (int j = jg * 48; j < jg * 48 + 48; ++j)
            s += bproj[j] * whead[j * 1000 + n];
    }
    red[t] = s;
    __syncthreads();
    for (int off = 128; off >= 16; off >>= 1) {
        if (t < off) red[t] += red[t + off];
        __syncthreads();
    }
    if (t < 16) {
        int nn = blockIdx.x * 16 + t;
        bf[nn] = (nn < 1000) ? (red[t] + bhead[nn]) : 0.f;
    }
}

// ---------------- out init / decode ----------------
__global__ __launch_bounds__(256) void k_init_out(u32t* __restrict__ o, int n) {
    int i = blockIdx.x * 256 + threadIdx.x;
    if (i < n) o[i] = 0u;
}
__global__ __launch_bounds__(256) void k_decode_out(u32t* __restrict__ o, int n) {
    int i = blockIdx.x * 256 + threadIdx.x;
    if (i < n) {
        float f = decf(o[i]);
        ((float*)o)[i] = f;
    }
}

// ---------------- GEMM v7: C[M,N] = A[M,K] * BT[N,K]^T, bf16 in, fp32 acc ----------------
// BM=128 x BN=128 x BK=64, 256 thr / 4 waves (2x2), wave tile 64x64, acc[4][4].
//
// Cross-round law (R1/R3/R4/R5): fewer+fatter barrier-pairs win (R1: 32 MFMA/pair,
// 12 pairs = best). m102's shape curve shows the same structure goes 320->833 TF
// purely from 1 -> 4-5 co-resident blocks/CU. R1's 64KB double-buffer capped
// residency at 2. v7 keeps R1's exact pair structure but reaches 32KB LDS via
// T14 reg-staging (single LDS buffer, prefetch tile t+1 in 32 VGPRs):
//   loop: issue 8 global_load_dwordx4 (t+1) -> compute t (16 ds_read + 32 MFMA)
//         -> lgkmcnt0+barrier (reads done) -> vmcnt0 (regs landed long ago)
//         -> 8 ds_write_b128 (swizzled, conflict-free) -> lgkmcnt0+barrier.
// 2 barriers/tile (same as R1). LDS 32KB -> residency cap 5 (LDS) / 4 (VGPR via
// __launch_bounds__(256,4)). Swizzle: byte ^= ((byte>>7)&3)<<4 on BOTH ds_write
// and ds_read addresses (R4-verified zero-conflict involution; with reg-staging
// the write side is free -- no global-source permutation needed).
#define BM 128
#define BN 128

#define QSCALE 0.18033688011112042f

// EPI 0: qkv scatter; EPI 2: +bias col-max atomic; EPI 3: plain bf16 store
template <int EPI>
__global__ __launch_bounds__(256, 4) void k_gemm10(const u16t* __restrict__ A, const u16t* __restrict__ BT,
                                                   int M, int N, int K,
                                                   u16t* __restrict__ Cb, const float* __restrict__ bias,
                                                   u32t* __restrict__ omax) {
    // single buffer: 2 kk-slabs x [128 rows][32 cols] each, 8KB/slab -> 16KB per matrix
    __shared__ alignas(16) u16t As[8192];
    __shared__ alignas(16) u16t Bs[8192];

    int tid = threadIdx.x;
    int lane = tid & 63, wid = tid >> 6;
    int wr = wid >> 1, wc = wid & 1;           // 2 x 2 wave grid
    int g = lane >> 4, l15 = lane & 15;

    // XCD-aware chunked swizzle (bijective: gridDim.x % 8 == 0 for all launches here)
    int nwg = gridDim.x;
    int bid = blockIdx.x;
    int wg = (bid & 7) * (nwg >> 3) + (bid >> 3);
    int nx = N >> 7;
    int bx = wg % nx, by = wg / nx;
    int m0 = by * BM, n0 = bx * BN;

    f32x4 acc[4][4];
    for (int i = 0; i < 4; i++)
        for (int j = 0; j < 4; j++) acc[i][j] = (f32x4){0.f, 0.f, 0.f, 0.f};

    // ---- staging map: chunk c = tid + 256*i (i=0..3), LDS byte = c*16 (then swizzled),
    // global row = ((c>>2)&127), col = (c>>9)*32 + (c&3)*8.  Collapses to 2 pointers
    // per matrix + {0,+32} column immediates; kk-slab picked by the LDS byte offset.
    int row0 = (tid >> 2) & 127;
    int cg = (tid & 3) * 8;
    const u16t* pA0 = A + (size_t)(m0 + row0) * K + cg;
    const u16t* pA1 = pA0 + (size_t)64 * K;
    const u16t* pB0 = BT + (size_t)(n0 + row0) * K + cg;
    const u16t* pB1 = pB0 + (size_t)64 * K;

    // ds_write base (bytes, swizzled; +4096*i offsets are swizzle-invariant)
    int wb = tid * 16;
    int wsw = wb ^ (((wb >> 7) & 3) << 4);
    char* wA = (char*)As + wsw;
    char* wB = (char*)Bs + wsw;

    // ds_read element offsets (swizzled); +i*512 elems (16 rows) and +4096 elems (kk1)
    // are swizzle-invariant (row bits 1-2 unchanged).
    int linA = ((wr * 64 + l15) << 6) + (g << 4);
    int aE = (linA ^ (((linA >> 7) & 3) << 4)) >> 1;
    int linB = ((wc * 64 + l15) << 6) + (g << 4);
    int bE = (linB ^ (((linB >> 7) & 3) << 4)) >> 1;

    short8 rA0, rA1, rA2, rA3, rB0, rB1, rB2, rB3;

#define LOADR() do { \
        rA0 = *(const short8*)pA0;        rA1 = *(const short8*)pA1; \
        rA2 = *(const short8*)(pA0 + 32); rA3 = *(const short8*)(pA1 + 32); \
        rB0 = *(const short8*)pB0;        rB1 = *(const short8*)pB1; \
        rB2 = *(const short8*)(pB0 + 32); rB3 = *(const short8*)(pB1 + 32); \
    } while (0)
#define WRITEL() do { \
        *(short8*)(wA +     0) = rA0; *(short8*)(wA +  4096) = rA1; \
        *(short8*)(wA +  8192) = rA2; *(short8*)(wA + 12288) = rA3; \
        *(short8*)(wB +     0) = rB0; *(short8*)(wB +  4096) = rB1; \
        *(short8*)(wB +  8192) = rB2; *(short8*)(wB + 12288) = rB3; \
    } while (0)
#define ADVANCE() do { pA0 += 64; pA1 += 64; pB0 += 64; pB1 += 64; } while (0)

    const int NT = K >> 6;  // K-tiles of 64

    // prologue: tile 0 regs -> LDS
    LOADR();
    asm volatile("s_waitcnt vmcnt(0)" ::: "memory");
    WRITEL();
    asm volatile("s_waitcnt lgkmcnt(0)" ::: "memory");
    __builtin_amdgcn_s_barrier();
    ADVANCE();

#pragma unroll 1
    for (int t = 0; t < NT; ++t) {
        const bool more = (t + 1 < NT);
        if (more) LOADR();   // issue tile t+1's 8 global loads; land during compute

        short8 af0, af1, af2, af3, bf0, bf1, bf2, bf3;
        // kk = 0
        af0 = *(const short8*)&As[aE];        af1 = *(const short8*)&As[aE + 512];
        af2 = *(const short8*)&As[aE + 1024]; af3 = *(const short8*)&As[aE + 1536];
        bf0 = *(const short8*)&Bs[bE];        bf1 = *(const short8*)&Bs[bE + 512];
        bf2 = *(const short8*)&Bs[bE + 1024]; bf3 = *(const short8*)&Bs[bE + 1536];
        acc[0][0] = MFMA16(af0, bf0, acc[0][0]); acc[0][1] = MFMA16(af0, bf1, acc[0][1]);
        acc[0][2] = MFMA16(af0, bf2, acc[0][2]); acc[0][3] = MFMA16(af0, bf3, acc[0][3]);
        acc[1][0] = MFMA16(af1, bf0, acc[1][0]); acc[1][1] = MFMA16(af1, bf1, acc[1][1]);
        acc[1][2] = MFMA16(af1, bf2, acc[1][2]); acc[1][3] = MFMA16(af1, bf3, acc[1][3]);
        acc[2][0] = MFMA16(af2, bf0, acc[2][0]); acc[2][1] = MFMA16(af2, bf1, acc[2][1]);
        acc[2][2] = MFMA16(af2, bf2, acc[2][2]); acc[2][3] = MFMA16(af2, bf3, acc[2][3]);
        acc[3][0] = MFMA16(af3, bf0, acc[3][0]); acc[3][1] = MFMA16(af3, bf1, acc[3][1]);
        acc[3][2] = MFMA16(af3, bf2, acc[3][2]); acc[3][3] = MFMA16(af3, bf3, acc[3][3]);
        // kk = 1
        af0 = *(const short8*)&As[aE + 4096]; af1 = *(const short8*)&As[aE + 4608];
        af2 = *(const short8*)&As[aE + 5120]; af3 = *(const short8*)&As[aE + 5632];
        bf0 = *(const short8*)&Bs[bE + 4096]; bf1 = *(const short8*)&Bs[bE + 4608];
        bf2 = *(const short8*)&Bs[bE + 5120]; bf3 = *(const short8*)&Bs[bE + 5632];
        acc[0][0] = MFMA16(af0, bf0, acc[0][0]); acc[0][1] = MFMA16(af0, bf1, acc[0][1]);
        acc[0][2] = MFMA16(af0, bf2, acc[0][2]); acc[0][3] = MFMA16(af0, bf3, acc[0][3]);
        acc[1][0] = MFMA16(af1, bf0, acc[1][0]); acc[1][1] = MFMA16(af1, bf1, acc[1][1]);
        acc[1][2] = MFMA16(af1, bf2, acc[1][2]); acc[1][3] = MFMA16(af1, bf3, acc[1][3]);
        acc[2][0] = MFMA16(af2, bf0, acc[2][0]); acc[2][1] = MFMA16(af2, bf1, acc[2][1]);
        acc[2][2] = MFMA16(af2, bf2, acc[2][2]); acc[2][3] = MFMA16(af2, bf3, acc[2][3]);
        acc[3][0] = MFMA16(af3, bf0, acc[3][0]); acc[3][1] = MFMA16(af3, bf1, acc[3][1]);
        acc[3][2] = MFMA16(af3, bf2, acc[3][2]); acc[3][3] = MFMA16(af3, bf3, acc[3][3]);

        asm volatile("s_waitcnt lgkmcnt(0)" ::: "memory");  // our ds_reads retired
        __builtin_amdgcn_s_barrier();                       // all waves done reading buffer

        if (more) {
            asm volatile("s_waitcnt vmcnt(0)" ::: "memory"); // t+1 regs landed (issued pre-compute)
            WRITEL();
            asm volatile("s_waitcnt lgkmcnt(0)" ::: "memory");
            __builtin_amdgcn_s_barrier();                    // writes visible to all waves
            ADVANCE();
        }
    }
#undef LOADR
#undef WRITEL
#undef ADVANCE

    if constexpr (EPI == 0) {
        // scatter: Q,K -> [B,H,N,64]; V -> V^T [B,H,64,2048] with kv bits2,3 swapped
        for (int i = 0; i < 4; i++)
            for (int j = 0; j < 4; j++)
                for (int r = 0; r < 4; r++) {
                    int row = m0 + wr * 64 + i * 16 + g * 4 + r;
                    int col = n0 + wc * 64 + j * 16 + l15;
                    int t = col / 768, rem = col - t * 768;
                    int hh = rem >> 6, d = rem & 63;
                    int bb = row >> 11, n = row & 2047;
                    float v = acc[i][j][r];
                    size_t idx;
                    if (t == 0) {
                        v *= QSCALE;
                        idx = ((size_t)(bb * 12 + hh)) * 131072 + (size_t)n * 64 + d;
                    } else if (t == 1) {
                        idx = ((size_t)(48 + bb * 12 + hh)) * 131072 + (size_t)n * 64 + d;
                    } else {
                        int np = (n & ~12) | ((n & 4) << 1) | ((n & 8) >> 1);
                        idx = ((size_t)(96 + bb * 12 + hh)) * 131072 + (size_t)d * 2048 + np;
                    }
                    Cb[idx] = f2b(v);
                }
    } else if constexpr (EPI == 3) {
        for (int i = 0; i < 4; i++)
            for (int j = 0; j < 4; j++)
                for (int r = 0; r < 4; r++) {
                    int row = m0 + wr * 64 + i * 16 + g * 4 + r;
                    int col = n0 + wc * 64 + j * 16 + l15;
                    Cb[(size_t)row * N + col] = f2b(acc[i][j][r]);
                }
    } else {
        __shared__ float smax[2][BN];
        float cmax[4];
        for (int j = 0; j < 4; j++) {
            float m = -3.0e38f;
            for (int i = 0; i < 4; i++)
                for (int r = 0; r < 4; r++) m = fmaxf(m, acc[i][j][r]);
            m = fmaxf(m, __shfl_xor(m, 16));
            m = fmaxf(m, __shfl_xor(m, 32));
            cmax[j] = m;
        }
        __syncthreads();
        if (lane < 16)
            for (int j = 0; j < 4; j++) smax[wr][wc * 64 + j * 16 + lane] = cmax[j];
        __syncthreads();
        if (tid < BN) {
            int col = n0 + tid;
            if (col < 1000) {
                float m = fmaxf(smax[0][tid], smax[1][tid]) + bias[col];
                int b = m0 >> 11;
                atomicMax(&omax[b * 1000 + col], encf(m));
            }
        }
    }
}

// ---------------- flash attention v7: fixed-max softmax with raw v_exp_f32, MFMA l-sum ----------------
__global__ __launch_bounds__(256) void k_flash(const u16t* __restrict__ QKV, u16t* __restrict__ AO) {
    __shared__ alignas(16) u16t Kc[3][4096];
    __shared__ alignas(16) u16t Vc[3][4096];

    const int tid = threadIdx.x;
    const int lane = tid & 63;
    const int h = lane >> 5;
    const int l31 = lane & 31;
    const int w = tid >> 6;
    const int wk = ((blockIdx.x & 7) * 96) + (blockIdx.x >> 3);
    const int qt = wk & 15;
    const int hb = wk >> 4;           // b*12 + head
    const int head = hb % 12, b = hb / 12;
    const u16t* Qg = QKV + ((size_t)hb) * 131072;
    const u16t* Kg = QKV + ((size_t)(48 + hb)) * 131072;
    const u16t* Vg = QKV + ((size_t)(96 + hb)) * 131072;  // V^T [64][2048], kv bits2,3 pre-swapped
    const int q0w = qt * 128 + w * 32;

    short8 qf[4];
#pragma unroll
    for (int ks = 0; ks < 4; ++ks)
        qf[ks] = *(const short8*)&Qg[(size_t)(q0w + l31) * 64 + ks * 16 + h * 8];
    asm volatile("s_waitcnt vmcnt(0)" ::: "memory");

    short8 vone;
#pragma unroll
    for (int e = 0; e < 8; ++e) vone[e] = (short)0x3F80;

    f32x16 o0, o1, lsum;
#pragma unroll
    for (int r = 0; r < 16; ++r) { o0[r] = 0.f; o1[r] = 0.f; lsum[r] = 0.f; }

    auto stage = [&](int bi, int kv0) {
#pragma unroll
        for (int c = 0; c < 2; ++c) {
            int ic = c * 256 + tid;
            int ss = ic >> 8, ks = (ic >> 6) & 3, l6 = ic & 63;
            int hh = l6 >> 5, lq = l6 & 31;
            const u16t* gs = Kg + ((size_t)(kv0 + ss * 32 + lq) << 6) + ks * 16 + hh * 8;
            gload16(gs, &Kc[bi][ic * 8]);
        }
#pragma unroll
        for (int c = 0; c < 2; ++c) {
            int ic = c * 256 + tid;
            int jb = ic >> 8, ks = (ic >> 6) & 3, l6 = ic & 63;
            int hh = l6 >> 5, ld = l6 & 31;
            const u16t* gs = Vg + (size_t)(jb * 32 + ld) * 2048 + kv0 + ks * 16 + hh * 8;
            gload16(gs, &Vc[bi][ic * 8]);
        }
    };

    stage(0, 0);
    stage(1, 64);

#pragma unroll 1
    for (int t = 0; t < 32; ++t) {
        const int cur = t % 3;
        if (t < 30) {
            stage((t + 2) % 3, (t + 2) * 64);
            asm volatile("s_waitcnt vmcnt(8)" ::: "memory");
        } else if (t == 30) {
            asm volatile("s_waitcnt vmcnt(4)" ::: "memory");
        } else {
            asm volatile("s_waitcnt vmcnt(0)" ::: "memory");
        }
        __builtin_amdgcn_s_barrier();

        const u16t* Kb = &Kc[cur][0];
        const u16t* Vb = &Vc[cur][0];

        f32x16 s0, s1;
#pragma unroll
        for (int r = 0; r < 16; ++r) { s0[r] = 0.f; s1[r] = 0.f; }
        __builtin_amdgcn_s_setprio(1);
#pragma unroll
        for (int ks = 0; ks < 4; ++ks) {
            short8 k0 = *(const short8*)&Kb[(ks * 64 + lane) * 8];
            short8 k1 = *(const short8*)&Kb[((4 + ks) * 64 + lane) * 8];
            s0 = MFMA32(k0, qf[ks], s0);
            s1 = MFMA32(k1, qf[ks], s1);
        }
        __builtin_amdgcn_s_setprio(0);

        // P = exp2(S), packed straight into A-fragments (fixed max = 0)
        short8 pf[4];
        auto packhalf = [&](const f32x16& sv, int half, int idx) {
            union { u32t wu[4]; short8 v; } u;
#pragma unroll
            for (int wq = 0; wq < 4; ++wq) {
                float lo = fexp2(sv[half * 8 + 2 * wq]);
                float hi = fexp2(sv[half * 8 + 2 * wq + 1]);
                asm("v_cvt_pk_bf16_f32 %0, %1, %2" : "=v"(u.wu[wq]) : "v"(lo), "v"(hi));
            }
            pf[idx] = u.v;
        };
        packhalf(s0, 0, 0);
        packhalf(s0, 1, 1);
        packhalf(s1, 0, 2);
        packhalf(s1, 1, 3);

        // PV: O += P * V ; l-sum via ones-operand MFMA
        __builtin_amdgcn_s_setprio(1);
#pragma unroll
        for (int ks = 0; ks < 4; ++ks) {
            short8 v0 = *(const short8*)&Vb[(ks * 64 + lane) * 8];
            short8 v1 = *(const short8*)&Vb[((4 + ks) * 64 + lane) * 8];
            o0 = MFMA32(pf[ks], v0, o0);
            o1 = MFMA32(pf[ks], v1, o1);
            lsum = MFMA32(pf[ks], vone, lsum);
        }
        __builtin_amdgcn_s_setprio(0);

        asm volatile("s_waitcnt lgkmcnt(0)" ::: "memory");
        __builtin_amdgcn_s_barrier();
    }

    // normalize + store
#pragma unroll
    for (int r = 0; r < 16; ++r) {
        int q = (r & 3) + 8 * (r >> 2) + 4 * h;
        float rn = 1.0f / lsum[r];
        u16t* dst = AO + (size_t)(b * 2048 + q0w + q) * 768 + head * 64;
        dst[l31] = f2b(o0[r] * rn);
        dst[32 + l31] = f2b(o1[r] * rn);
    }
}

extern "C" void kernel_launch(void* const* d_in, const int* in_sizes, int n_in,
                              void* d_out, int out_size, void* d_ws, size_t ws_size,
                              hipStream_t stream) {
    const float* x = (const float*)d_in[0];
    const float* w_qkv = (const float*)d_in[1];
    const float* w_proj = (const float*)d_in[2];
    const float* b_proj = (const float*)d_in[3];
    const float* w_head = (const float*)d_in[4];
    const float* b_head = (const float*)d_in[5];

    char* ws = (char*)d_ws;
    u16t* xb = (u16t*)(ws);                        // 8192x768 bf16      12,582,912 B
    u16t* wqkvT = (u16t*)(ws + 12582912);          // 2304x768           3,538,944
    u16t* wheadT = (u16t*)(ws + 16121856);         // 1024x768 (padded)  1,572,864
    u16t* wprojb = (u16t*)(ws + 17694720);         // 768x768 row-major  1,179,648
    u16t* qkv = (u16t*)(ws + 18874368);            // [3,4,12,...]       37,748,736
    u16t* ao = (u16t*)(ws + 56623104);             // 8192x768           12,582,912
    u16t* WfT = (u16t*)(ws + 69206016);            // 1024x768           1,572,864
    float* bias_f = (float*)(ws + 70778880);       // 1024 f32           4,096

    dim3 tb(32, 8);
    k_cast_x<<<6144, 256, 0, stream>>>(x, xb);
    k_cast_x<<<576, 256, 0, stream>>>(w_proj, (u16t*)wprojb);
    k_transpose<<<dim3(2304 / 32, 768 / 32), tb, 0, stream>>>(w_qkv, wqkvT, 768, 2304, 2304);
    k_transpose<<<dim3(1024 / 32, 768 / 32), tb, 0, stream>>>(w_head, wheadT, 768, 1000, 1024);
    k_init_out<<<16, 256, 0, stream>>>((u32t*)d_out, 4000);
    k_bias_f<<<64, 256, 0, stream>>>(b_proj, w_head, b_head, bias_f);

    // WfT[n][k] = sum_j whead[j][n] * wproj[k][j]  (fused proj@head weight, transposed)
    // grid 48 blocks (%8==0)
    k_gemm10<3><<<48, 256, 0, stream>>>(wheadT, wprojb, 1024, 768, 768, WfT, nullptr, nullptr);

    // qkv = x @ w_qkv  (scatter: Q scaled, K row-major, V transposed + kv-perm)
    // grid 18x64 = 1152 blocks (%8==0)
    k_gemm10<0><<<1152, 256, 0, stream>>>(xb, wqkvT, 8192, 2304, 768, qkv, nullptr, nullptr);
    // attention
    k_flash<<<768, 256, 0, stream>>>(qkv, ao);
    // fused (proj+head) + bias + max-over-N (atomic, encoded)
    // grid 8x64 = 512 blocks (%8==0)
    k_gemm10<2><<<512, 256, 0, stream>>>(ao, WfT, 8192, 1024, 768, nullptr, bias_f, (u32t*)d_out);

    k_decode_out<<<16, 256, 0, stream>>>((u32t*)d_out, 4000);
}